// Round 11
// baseline (3129.627 us; speedup 1.0000x reference)
//
#include <hip/hip_runtime.h>
#include <stdint.h>

// Bidirectional GRU, 6 layers, H=256, S=512, B=10, fp32 in/out, bf16 MFMA.
// 7 scans + 21 helpers (r9/r10-exact helper side, swizzled slot image).
// THIS ROUND — deepen the two remaining latency budgets on the r10 skeleton:
//   r10 (role-split, -8%) left one hard per-step wait: staging waves'
//   WVC(8/9) retires dma16(t+1) 1.9 steps after issue => step ~= L_dma/1.9
//   (implies L_dma ~5.6us SC1/MALL). Fix:
//   1) depth-3 prefetch, 4 LDS slots (148,000B): dma16(t+3) issued at A(t);
//      w0 WVC(17) / w1-3 WVC(16) keep TWO steps' DMAs in flight => dma16
//      retires 2.9 steps after issue. Mirror dma4 (slot t+5 at A(t), ring 8)
//      retires with step t-2's ops => fresh at A(t+2) read.
//   2) htag shift t-4 -> t-6 on wave4 with WVC(8) (h-store(t-6) has >=8
//      wave4-ops after it by A(t)) => store-ack bound L/4.7.
//   Store waves 4-7 still float (no F wait). Edges t<6 / t>=SEQ-7 full-drain.
// LDS swizzles (r9), role split (r10), helpers (r6/r9) unchanged.

typedef short short8 __attribute__((ext_vector_type(8)));
typedef float floatx4 __attribute__((ext_vector_type(4)));
typedef unsigned long long u64;
typedef unsigned int u32;
typedef unsigned short u16;

#define SEQ 512

// ws: gring 7*32 slots x 32KB (rz bf16 swz + nx f32 swz) = 7.34MB
//     hh   scans 0..4 [t:512][b:16][ch:128] bf16 = 10.5MB
//     tags u32: gtag[7][32] @0 ; htag[5][512] @256 ; cparr[7] @2816
#define GSLOT_U64 4096
#define GRING_U64 (7 * 32 * GSLOT_U64)
#define HH_U16 (5 * 512 * 2048)
#define TAGS_OFF_B ((size_t)GRING_U64 * 8 + (size_t)HH_U16 * 2)

// swizzles (bijective within the 32KB slot image; r9-verified)
#define RZ_OFF(col, quad)  (((col)*32 + (quad)*8) ^ ((((col)>>2)&3)<<3))
#define NX_OFF(j, quad)    (16384 + (((j)*64 + (quad)*16) ^ ((((j)>>1)&3)<<4)))

__device__ __forceinline__ u16 f2bf(float f){ union{float f;u32 i;}v; v.f=f; u32 u=v.i; u += 0x7fffu + ((u>>16)&1u); return (u16)(u>>16); }
__device__ __forceinline__ float bf2f(u16 h){ union{u32 i;float f;}v; v.i=((u32)h)<<16; return v.f; }
__device__ __forceinline__ short8 ld8f(const float* p){
    float4 a=*(const float4*)p, b=*(const float4*)(p+4);
    short8 r; r[0]=(short)f2bf(a.x); r[1]=(short)f2bf(a.y); r[2]=(short)f2bf(a.z); r[3]=(short)f2bf(a.w);
    r[4]=(short)f2bf(b.x); r[5]=(short)f2bf(b.y); r[6]=(short)f2bf(b.z); r[7]=(short)f2bf(b.w); return r;
}
__device__ __forceinline__ short8 pk2(u64 a, u64 b){ union{u64 q[2]; short8 s;}v; v.q[0]=a; v.q[1]=b; return v.s; }
__device__ __forceinline__ u64 pack4bf(floatx4 a){
    return (u64)f2bf(a[0]) | ((u64)f2bf(a[1])<<16) | ((u64)f2bf(a[2])<<32) | ((u64)f2bf(a[3])<<48);
}
__device__ __forceinline__ float rcp_(float x){ float r; asm("v_rcp_f32 %0, %1" : "=v"(r) : "v"(x)); return r; }
__device__ __forceinline__ float sigmoidf_(float x){ return rcp_(1.0f + __expf(-x)); }
__device__ __forceinline__ float tanhf_(float x){ return 1.0f - 2.0f*rcp_(__expf(2.0f*x) + 1.0f); }

#define ALD(p)    __hip_atomic_load((p), __ATOMIC_RELAXED, __HIP_MEMORY_SCOPE_AGENT)
#define AST(p,v)  __hip_atomic_store((p),(v),__ATOMIC_RELAXED,__HIP_MEMORY_SCOPE_AGENT)
__device__ __forceinline__ void wait_vm0(){ asm volatile("s_waitcnt vmcnt(0)" ::: "memory"); }
#define WVC(n) asm volatile("s_waitcnt vmcnt(" #n ")" ::: "memory")
__device__ __forceinline__ void lgkm_barrier(){ asm volatile("s_waitcnt lgkmcnt(0)\n\ts_barrier" ::: "memory"); }

__device__ __forceinline__ void st16_sc1(void* p, floatx4 v){
    asm volatile("global_store_dwordx4 %0, %1, off sc1" :: "v"(p), "v"(v) : "memory");
}
__device__ __forceinline__ void dma16(const void* g, void* l) {
    __builtin_amdgcn_global_load_lds(
        reinterpret_cast<const __attribute__((address_space(1))) unsigned int*>(
            (uintptr_t)g),
        reinterpret_cast<__attribute__((address_space(3))) unsigned int*>(
            (uintptr_t)l), 16, 0, 16);
}
__device__ __forceinline__ void dma4(const void* g, void* l) {
    __builtin_amdgcn_global_load_lds(
        reinterpret_cast<const __attribute__((address_space(1))) unsigned int*>(
            (uintptr_t)g),
        reinterpret_cast<__attribute__((address_space(3))) unsigned int*>(
            (uintptr_t)l), 4, 0, 16);
}

__global__ __launch_bounds__(512, 2)
void gru_pipeline(const float* __restrict__ x,
                  const float* __restrict__ wihl0,
                  const float* __restrict__ wihrest,
                  const float* __restrict__ whh,
                  float* __restrict__ out,
                  u64* __restrict__ gring,
                  u16* __restrict__ hhb,
                  u32* __restrict__ tags)
{
    __shared__ u64 smem_[18500];   // 148,000 B: gbuf 4x32768 + hbuf 16,896 + tagmir 32
    const int blk  = blockIdx.x;
    const int tid  = threadIdx.x;
    const int w    = tid >> 6;
    const int lane = tid & 63;
    const int n16  = lane & 15;
    const int quad = lane >> 4;
    u32* cparr = tags + 2816;

    if (blk < 7) {
        // ================= SCAN: one 512-thread WG per scan =================
        const int s = blk;
        const int wu = __builtin_amdgcn_readfirstlane(tid) >> 6;   // wave idx, SGPR
        const int layer = (s==6)?5:s, dir=(s==6)?1:0;
        const float* whhp = whh + ((size_t)(layer*2+dir))*768*256;

        short8 bh[6][8];
#pragma unroll
        for (int g=0; g<3; ++g)
#pragma unroll
        for (int u=0; u<2; ++u) {
            const int row = g*256 + 32*w + 16*u + n16;
#pragma unroll
            for (int q=0; q<8; ++q)
                bh[g*2+u][q] = ld8f(whhp + (size_t)row*256 + q*32 + quad*8);
        }

        char* gb   = (char*)smem_;                      // gate slots: [4][32768 B]
        u16*  hbuf = (u16*)(gb + 131072);               // [2][16][264] bf16
        u32*  tagmir = (u32*)((char*)smem_ + 147968);   // [8] gtag mirror ring
        for (int i=tid; i<8448; i+=512) hbuf[i] = 0;    // h(-1)=0 (both slots)

        u32* gtp = tags + s*32;
        u32* htp = tags + 256 + s*512;

        // prologue: staging threads stage gates(0),(1),(2); mirror tags 3,4
        {
#pragma unroll
            for (int p=0; p<3; ++p) {
                int gd=0;
                while (ALD(gtp + p) != (u32)(p+1)){ if(++gd>3000000) break; __builtin_amdgcn_s_sleep(2); }
                if (tid < 256) {
                    const char* sg = (const char*)(gring + (size_t)(s*32 + p)*GSLOT_U64);
#pragma unroll
                    for (int r=0; r<8; ++r) dma16(sg + (r*256+tid)*16, gb + p*32768 + (r*256+tid)*16);
                }
            }
            if (tid==0) { dma4(gtp + 3, tagmir + 3); dma4(gtp + 4, tagmir + 4); }
            wait_vm0(); lgkm_barrier();
        }

        for (int t=0; t<SEQ; ++t) {
            const u16* hbP = hbuf + (t&1)*4224;
            // A: staging waves (0-3): mirror check slot t+3, dma4(t+5), dma16(t+3).
            // Slot (t+3)&3's previous readers = D(t-1), barrier-separated.
            if (t+3 < SEQ && wu < 4) {
                if (tagmir[(t+3)&7] != (u32)(t+4)) {    // rare: warm-up/helper-late
                    int gd=0;
                    while (ALD(gtp + ((t+3)&31)) != (u32)(t+4)){ if(++gd>3000000) break; __builtin_amdgcn_s_sleep(1); }
                }
                if (wu==0 && lane==0 && t+5 < SEQ)
                    dma4(gtp + ((t+5)&31), tagmir + ((t+5)&7));
                const char* sg = (const char*)(gring + (size_t)(s*32 + ((t+3)&31))*GSLOT_U64);
                char* dg = gb + ((t+3)&3)*32768;
#pragma unroll
                for (int r=0; r<8; ++r) dma16(sg + (r*256+tid)*16, dg + (r*256+tid)*16);
            }
            // A': wave 4 owns the tags. htag(t-6): h-store(t-6) issued B(t-5)
            // has >=8 wave4-ops after it (4 steps x {htag,hst}) => WVC(8).
            if (wu == 4) {
                if (s<=4 && t>=6) { WVC(8); AST(htp + (t-6), (u32)(t-5)); }
                if ((t&3)==0) AST(cparr + s, (u32)(t+1));
            }

            // B: store waves (4-7) publish h(t-1) / out(t-1) from slot t&1
            if (t >= 1 && wu >= 4) {
                if (s<=4) {
                    const int idx = tid - 256;          // 0..255
                    const int b = idx & 15, k = (idx >> 4) & 15;
                    char* hq = (char*)(hhb + (size_t)s*1048576 + (size_t)(t-1)*2048);
                    st16_sc1(hq + b*256 + k*16, *(const floatx4*)(hbP + b*264 + 8*k));
                } else {
                    const int off = (s==6)?256:0;
#pragma unroll
                    for (int k=0;k<3;++k) {
                        const int idx = (tid-256) + 256*k;   // 0..767, need <640
                        if (idx < 640) {
                            const int b = idx >> 6, jg = (idx & 63)*4;
                            union { u64 q; u16 h[4]; } v; v.q = *(const u64*)(hbP + b*264 + jg);
                            float4 o; o.x=bf2f(v.h[0]); o.y=bf2f(v.h[1]); o.z=bf2f(v.h[2]); o.w=bf2f(v.h[3]);
                            *(float4*)(out + (size_t)(t-1)*5120 + (size_t)b*512 + off + jg) = o;
                        }
                    }
                }
            }
            // D: acc init (rz swizzled) + 48 MFMAs over K=256 (all waves)
            const char* g0 = gb + (t&3)*32768;
            floatx4 acc[6];
#pragma unroll
            for (int g=0; g<2; ++g)
#pragma unroll
            for (int u=0; u<2; ++u) {
                const int col = g*256 + 32*w + 16*u + n16;
                const u64 gw = *(const u64*)(g0 + RZ_OFF(col, quad));
#pragma unroll
                for (int r=0; r<4; ++r) acc[g*2+u][r] = bf2f((u16)(gw >> (16*r)));
            }
            acc[4] = (floatx4){0.f,0.f,0.f,0.f};
            acc[5] = (floatx4){0.f,0.f,0.f,0.f};
#pragma unroll
            for (int q=0; q<8; ++q) {
                short8 ah = *(const short8*)(hbP + n16*264 + q*32 + quad*8);
#pragma unroll
                for (int m=0; m<6; ++m)
                    acc[m] = __builtin_amdgcn_mfma_f32_16x16x32_bf16(ah, bh[m][q], acc[m], 0,0,0);
            }
            // E: nonlinearity (nx swizzled), h(t) -> LDS slot (t+1)&1
            u16* hbN = hbuf + ((t+1)&1)*4224;
#pragma unroll
            for (int u=0; u<2; ++u) {
                const int j = 32*w + 16*u + n16;
                const floatx4 nx4 = *(const floatx4*)(g0 + NX_OFF(j, quad));
#pragma unroll
                for (int r=0; r<4; ++r) {
                    const int b = quad*4 + r;
                    float rr = sigmoidf_(acc[u][r]);
                    float zz = sigmoidf_(acc[2+u][r]);
                    float nn = tanhf_(nx4[r] + rr*acc[4+u][r]);
                    float hp = bf2f(hbP[b*264 + j]);
                    float hn = nn + zz*(hp - nn);
                    hbN[b*264 + j] = f2bf(hn);
                }
            }
            // F: staging waves keep TWO steps' DMAs in flight.
            // w0: 9 ops/step (dma4+8dma16) -> WVC(17) retires step t-2's ops
            //     (dma16(t+1) for D(t+1); dma4(t+3) read at A(t+1)).
            // w1-3: 8 ops/step -> WVC(16). Store waves: no wait.
            if (t < 6 || t >= SEQ-7) {
                wait_vm0();
            } else if (wu == 0) {
                WVC(17);
            } else if (wu < 4) {
                WVC(16);
            }                               // wu>=4: acks float
            lgkm_barrier();
        }
        // epilogue: h(511)/out(511) live in slot (512&1)=0
        const u16* hbL = hbuf;
        if (wu >= 4) {
            if (s<=4) {
                const int idx = tid - 256;
                const int b = idx & 15, k = (idx >> 4) & 15;
                char* hq = (char*)(hhb + (size_t)s*1048576 + (size_t)(SEQ-1)*2048);
                st16_sc1(hq + b*256 + k*16, *(const floatx4*)(hbL + b*264 + 8*k));
            } else {
                const int off = (s==6)?256:0;
#pragma unroll
                for (int k=0;k<3;++k) {
                    const int idx = (tid-256) + 256*k;
                    if (idx < 640) {
                        const int b = idx >> 6, jg = (idx & 63)*4;
                        union { u64 q; u16 h[4]; } v; v.q = *(const u64*)(hbL + b*264 + jg);
                        float4 o; o.x=bf2f(v.h[0]); o.y=bf2f(v.h[1]); o.z=bf2f(v.h[2]); o.w=bf2f(v.h[3]);
                        *(float4*)(out + (size_t)(SEQ-1)*5120 + (size_t)b*512 + off + jg) = o;
                    }
                }
            }
        }
        wait_vm0(); lgkm_barrier();
        if (tid==0 && s<=4) {
            AST(htp + 506, 507u); AST(htp + 507, 508u);
            AST(htp + 508, 509u); AST(htp + 509, 510u);
            AST(htp + 510, 511u); AST(htp + 511, 512u);
        }
        return;
    }

    // ================= HELPERS: gates_x producers (3 WGs/stream, r9-exact) ========
    int sh, t0;
    if (blk < 10)      { sh = 0;               t0 = blk - 7;      }
    else if (blk < 25) { sh = 1 + (blk-10)/3;  t0 = (blk-10)%3;   }
    else               { sh = 6;               t0 = blk - 25;     }

    const int layer = (sh==6)?5:sh, dir=(sh==6)?1:0;
    const float* wihp; int stride;
    if (layer==0){ wihp = wihl0 + (size_t)dir*768*128; stride=128; }
    else         { wihp = wihrest + ((size_t)((layer-1)*2+dir))*768*512; stride=512; }

    short8 bxf[6][4];
#pragma unroll
    for (int i=0; i<6; ++i) {
        const int col = (w*6+i)*16 + n16;
#pragma unroll
        for (int q=0; q<4; ++q)
            bxf[i][q] = ld8f(wihp + (size_t)col*stride + q*32 + quad*8);
    }
    char* tb = (char*)smem_;               // 32 KB slot image
    const int bmA = (n16>9)?9:n16;
    const int lsrc = (sh==6)? 4 : (sh-1);
    u32* gtp_sh = tags + sh*32;

    // Software-pipelined publish: stores at iter t, tag at t+3.
    int tprev = -1;
    for (int t = t0; t < SEQ; t += 3) {
        if (t >= 32) {
            int gd=0;
            while ((int)ALD(cparr + sh) < t-24){ if(++gd>1000000) break; __builtin_amdgcn_s_sleep(8); }
        }
        if (tprev >= 0) {
            wait_vm0();
            __syncthreads();
            if (tid==0) AST(gtp_sh + (tprev&31), (u32)(tprev+1));
        }
        short8 ax[4];
        if (sh == 0) {
            const float* xr = x + (size_t)t*1280 + (size_t)bmA*128;
#pragma unroll
            for (int q=0; q<4; ++q) ax[q] = ld8f(xr + q*32 + quad*8);
        } else {
            const int srct = (sh==6)? (SEQ-1-t) : t;
            int gd=0;
            while (ALD(tags + 256 + lsrc*512 + srct) != (u32)(srct+1)){ if(++gd>3000000) break; __builtin_amdgcn_s_sleep(4); }
            const u64* hq = (const u64*)(hhb + (size_t)lsrc*1048576 + (size_t)srct*2048);
#pragma unroll
            for (int q=0; q<4; ++q) {
                u64 a = ALD(hq + n16*32 + q*8 + quad*2);
                u64 b = ALD(hq + n16*32 + q*8 + quad*2 + 1);
                ax[q] = pk2(a, b);
            }
        }
        floatx4 acc[6];
#pragma unroll
        for (int i=0; i<6; ++i) acc[i] = (floatx4){0.f,0.f,0.f,0.f};
#pragma unroll
        for (int q=0; q<4; ++q)
#pragma unroll
            for (int i=0; i<6; ++i)
                acc[i] = __builtin_amdgcn_mfma_f32_16x16x32_bf16(ax[q], bxf[i][q], acc[i], 0,0,0);

        // slot image (SWIZZLED): rz bf16 + nx f32; matches scan-side reads
#pragma unroll
        for (int i=0; i<6; ++i) {
            const int col = (w*6+i)*16 + n16;
            if (col < 512) *(u64*)(tb + RZ_OFF(col, quad)) = pack4bf(acc[i]);
            else           *(floatx4*)(tb + NX_OFF(col-512, quad)) = acc[i];
        }
        __syncthreads();
        char* gq = (char*)(gring + (size_t)(sh*32 + (t&31))*GSLOT_U64);
#pragma unroll
        for (int k=0;k<4;++k)
            st16_sc1(gq + tid*64 + k*16, *(const floatx4*)((const char*)tb + tid*64 + k*16));
        tprev = t;
    }
    wait_vm0(); __syncthreads();
    if (tid==0 && tprev>=0) AST(gtp_sh + (tprev&31), (u32)(tprev+1));
}

extern "C" void kernel_launch(void* const* d_in, const int* in_sizes, int n_in,
                              void* d_out, int out_size, void* d_ws, size_t ws_size,
                              hipStream_t stream) {
    (void)in_sizes; (void)n_in; (void)out_size; (void)ws_size;
    const float* x       = (const float*)d_in[0];
    const float* wihl0   = (const float*)d_in[1];
    const float* wihrest = (const float*)d_in[2];
    const float* whh     = (const float*)d_in[3];
    float* out = (float*)d_out;
    u64* gring = (u64*)d_ws;
    u16* hhb   = (u16*)((char*)d_ws + (size_t)GRING_U64*8);
    u32* tags  = (u32*)((char*)d_ws + TAGS_OFF_B);

    // No memset: 0xAAAAAAAA poison never equals a valid tag (1..512);
    // flow-control reads cast to int; stale/poison LDS tag mirrors => bounded
    // slow poll (no deadlock; all barriers unconditional).
    gru_pipeline<<<dim3(28), dim3(512), 0, stream>>>(x, wihl0, wihrest, whh, out,
                                                     gring, hhb, tags);
}

// Round 12
// 3024.826 us; speedup vs baseline: 1.0346x; 1.0346x over previous
//
#include <hip/hip_runtime.h>
#include <stdint.h>

// Bidirectional GRU, 6 layers, H=256, S=512, B=10, fp32 in/out, bf16 MFMA.
// 7 scans (r11-exact) + 42 helpers (6/stream, r9-swizzled slot image).
// THIS ROUND — single variable: helpers 3 -> 6 per stream.
//   r11 (consumer DMA slack 1.9->2.9) = NULL => consumer slack not binding.
//   Reconstruction: helper iteration T_h ~ 9us (store-ack wait_vm0 + exposed
//   h-load ALD RTT + compute) / 3 WGs = 3.0us slot interval = EXACTLY the
//   r10/r11 steady step (2.99-3.0). The consumer improved past the producer
//   rate between r7 and r10 (r7's 6-helper null was on the 3.37us r6
//   consumer — both regimes consumer-bound then). Now producer-bound =>
//   halve the producer interval. Scan side byte-identical to r11.

typedef short short8 __attribute__((ext_vector_type(8)));
typedef float floatx4 __attribute__((ext_vector_type(4)));
typedef unsigned long long u64;
typedef unsigned int u32;
typedef unsigned short u16;

#define SEQ 512

// ws: gring 7*32 slots x 32KB (rz bf16 swz + nx f32 swz) = 7.34MB
//     hh   scans 0..4 [t:512][b:16][ch:128] bf16 = 10.5MB
//     tags u32: gtag[7][32] @0 ; htag[5][512] @256 ; cparr[7] @2816
#define GSLOT_U64 4096
#define GRING_U64 (7 * 32 * GSLOT_U64)
#define HH_U16 (5 * 512 * 2048)
#define TAGS_OFF_B ((size_t)GRING_U64 * 8 + (size_t)HH_U16 * 2)

// swizzles (bijective within the 32KB slot image; r9-verified)
#define RZ_OFF(col, quad)  (((col)*32 + (quad)*8) ^ ((((col)>>2)&3)<<3))
#define NX_OFF(j, quad)    (16384 + (((j)*64 + (quad)*16) ^ ((((j)>>1)&3)<<4)))

__device__ __forceinline__ u16 f2bf(float f){ union{float f;u32 i;}v; v.f=f; u32 u=v.i; u += 0x7fffu + ((u>>16)&1u); return (u16)(u>>16); }
__device__ __forceinline__ float bf2f(u16 h){ union{u32 i;float f;}v; v.i=((u32)h)<<16; return v.f; }
__device__ __forceinline__ short8 ld8f(const float* p){
    float4 a=*(const float4*)p, b=*(const float4*)(p+4);
    short8 r; r[0]=(short)f2bf(a.x); r[1]=(short)f2bf(a.y); r[2]=(short)f2bf(a.z); r[3]=(short)f2bf(a.w);
    r[4]=(short)f2bf(b.x); r[5]=(short)f2bf(b.y); r[6]=(short)f2bf(b.z); r[7]=(short)f2bf(b.w); return r;
}
__device__ __forceinline__ short8 pk2(u64 a, u64 b){ union{u64 q[2]; short8 s;}v; v.q[0]=a; v.q[1]=b; return v.s; }
__device__ __forceinline__ u64 pack4bf(floatx4 a){
    return (u64)f2bf(a[0]) | ((u64)f2bf(a[1])<<16) | ((u64)f2bf(a[2])<<32) | ((u64)f2bf(a[3])<<48);
}
__device__ __forceinline__ float rcp_(float x){ float r; asm("v_rcp_f32 %0, %1" : "=v"(r) : "v"(x)); return r; }
__device__ __forceinline__ float sigmoidf_(float x){ return rcp_(1.0f + __expf(-x)); }
__device__ __forceinline__ float tanhf_(float x){ return 1.0f - 2.0f*rcp_(__expf(2.0f*x) + 1.0f); }

#define ALD(p)    __hip_atomic_load((p), __ATOMIC_RELAXED, __HIP_MEMORY_SCOPE_AGENT)
#define AST(p,v)  __hip_atomic_store((p),(v),__ATOMIC_RELAXED,__HIP_MEMORY_SCOPE_AGENT)
__device__ __forceinline__ void wait_vm0(){ asm volatile("s_waitcnt vmcnt(0)" ::: "memory"); }
#define WVC(n) asm volatile("s_waitcnt vmcnt(" #n ")" ::: "memory")
__device__ __forceinline__ void lgkm_barrier(){ asm volatile("s_waitcnt lgkmcnt(0)\n\ts_barrier" ::: "memory"); }

__device__ __forceinline__ void st16_sc1(void* p, floatx4 v){
    asm volatile("global_store_dwordx4 %0, %1, off sc1" :: "v"(p), "v"(v) : "memory");
}
__device__ __forceinline__ void dma16(const void* g, void* l) {
    __builtin_amdgcn_global_load_lds(
        reinterpret_cast<const __attribute__((address_space(1))) unsigned int*>(
            (uintptr_t)g),
        reinterpret_cast<__attribute__((address_space(3))) unsigned int*>(
            (uintptr_t)l), 16, 0, 16);
}
__device__ __forceinline__ void dma4(const void* g, void* l) {
    __builtin_amdgcn_global_load_lds(
        reinterpret_cast<const __attribute__((address_space(1))) unsigned int*>(
            (uintptr_t)g),
        reinterpret_cast<__attribute__((address_space(3))) unsigned int*>(
            (uintptr_t)l), 4, 0, 16);
}

__global__ __launch_bounds__(512, 2)
void gru_pipeline(const float* __restrict__ x,
                  const float* __restrict__ wihl0,
                  const float* __restrict__ wihrest,
                  const float* __restrict__ whh,
                  float* __restrict__ out,
                  u64* __restrict__ gring,
                  u16* __restrict__ hhb,
                  u32* __restrict__ tags)
{
    __shared__ u64 smem_[18500];   // 148,000 B: gbuf 4x32768 + hbuf 16,896 + tagmir 32
    const int blk  = blockIdx.x;
    const int tid  = threadIdx.x;
    const int w    = tid >> 6;
    const int lane = tid & 63;
    const int n16  = lane & 15;
    const int quad = lane >> 4;
    u32* cparr = tags + 2816;

    if (blk < 7) {
        // ================= SCAN: one 512-thread WG per scan (r11-exact) ==========
        const int s = blk;
        const int wu = __builtin_amdgcn_readfirstlane(tid) >> 6;   // wave idx, SGPR
        const int layer = (s==6)?5:s, dir=(s==6)?1:0;
        const float* whhp = whh + ((size_t)(layer*2+dir))*768*256;

        short8 bh[6][8];
#pragma unroll
        for (int g=0; g<3; ++g)
#pragma unroll
        for (int u=0; u<2; ++u) {
            const int row = g*256 + 32*w + 16*u + n16;
#pragma unroll
            for (int q=0; q<8; ++q)
                bh[g*2+u][q] = ld8f(whhp + (size_t)row*256 + q*32 + quad*8);
        }

        char* gb   = (char*)smem_;                      // gate slots: [4][32768 B]
        u16*  hbuf = (u16*)(gb + 131072);               // [2][16][264] bf16
        u32*  tagmir = (u32*)((char*)smem_ + 147968);   // [8] gtag mirror ring
        for (int i=tid; i<8448; i+=512) hbuf[i] = 0;    // h(-1)=0 (both slots)

        u32* gtp = tags + s*32;
        u32* htp = tags + 256 + s*512;

        // prologue: staging threads stage gates(0),(1),(2); mirror tags 3,4
        {
#pragma unroll
            for (int p=0; p<3; ++p) {
                int gd=0;
                while (ALD(gtp + p) != (u32)(p+1)){ if(++gd>3000000) break; __builtin_amdgcn_s_sleep(2); }
                if (tid < 256) {
                    const char* sg = (const char*)(gring + (size_t)(s*32 + p)*GSLOT_U64);
#pragma unroll
                    for (int r=0; r<8; ++r) dma16(sg + (r*256+tid)*16, gb + p*32768 + (r*256+tid)*16);
                }
            }
            if (tid==0) { dma4(gtp + 3, tagmir + 3); dma4(gtp + 4, tagmir + 4); }
            wait_vm0(); lgkm_barrier();
        }

        for (int t=0; t<SEQ; ++t) {
            const u16* hbP = hbuf + (t&1)*4224;
            // A: staging waves (0-3): mirror check slot t+3, dma4(t+5), dma16(t+3).
            if (t+3 < SEQ && wu < 4) {
                if (tagmir[(t+3)&7] != (u32)(t+4)) {    // rare: warm-up/helper-late
                    int gd=0;
                    while (ALD(gtp + ((t+3)&31)) != (u32)(t+4)){ if(++gd>3000000) break; __builtin_amdgcn_s_sleep(1); }
                }
                if (wu==0 && lane==0 && t+5 < SEQ)
                    dma4(gtp + ((t+5)&31), tagmir + ((t+5)&7));
                const char* sg = (const char*)(gring + (size_t)(s*32 + ((t+3)&31))*GSLOT_U64);
                char* dg = gb + ((t+3)&3)*32768;
#pragma unroll
                for (int r=0; r<8; ++r) dma16(sg + (r*256+tid)*16, dg + (r*256+tid)*16);
            }
            // A': wave 4 owns the tags. htag(t-6): WVC(8) then publish.
            if (wu == 4) {
                if (s<=4 && t>=6) { WVC(8); AST(htp + (t-6), (u32)(t-5)); }
                if ((t&3)==0) AST(cparr + s, (u32)(t+1));
            }

            // B: store waves (4-7) publish h(t-1) / out(t-1) from slot t&1
            if (t >= 1 && wu >= 4) {
                if (s<=4) {
                    const int idx = tid - 256;          // 0..255
                    const int b = idx & 15, k = (idx >> 4) & 15;
                    char* hq = (char*)(hhb + (size_t)s*1048576 + (size_t)(t-1)*2048);
                    st16_sc1(hq + b*256 + k*16, *(const floatx4*)(hbP + b*264 + 8*k));
                } else {
                    const int off = (s==6)?256:0;
#pragma unroll
                    for (int k=0;k<3;++k) {
                        const int idx = (tid-256) + 256*k;   // 0..767, need <640
                        if (idx < 640) {
                            const int b = idx >> 6, jg = (idx & 63)*4;
                            union { u64 q; u16 h[4]; } v; v.q = *(const u64*)(hbP + b*264 + jg);
                            float4 o; o.x=bf2f(v.h[0]); o.y=bf2f(v.h[1]); o.z=bf2f(v.h[2]); o.w=bf2f(v.h[3]);
                            *(float4*)(out + (size_t)(t-1)*5120 + (size_t)b*512 + off + jg) = o;
                        }
                    }
                }
            }
            // D: acc init (rz swizzled) + 48 MFMAs over K=256 (all waves)
            const char* g0 = gb + (t&3)*32768;
            floatx4 acc[6];
#pragma unroll
            for (int g=0; g<2; ++g)
#pragma unroll
            for (int u=0; u<2; ++u) {
                const int col = g*256 + 32*w + 16*u + n16;
                const u64 gw = *(const u64*)(g0 + RZ_OFF(col, quad));
#pragma unroll
                for (int r=0; r<4; ++r) acc[g*2+u][r] = bf2f((u16)(gw >> (16*r)));
            }
            acc[4] = (floatx4){0.f,0.f,0.f,0.f};
            acc[5] = (floatx4){0.f,0.f,0.f,0.f};
#pragma unroll
            for (int q=0; q<8; ++q) {
                short8 ah = *(const short8*)(hbP + n16*264 + q*32 + quad*8);
#pragma unroll
                for (int m=0; m<6; ++m)
                    acc[m] = __builtin_amdgcn_mfma_f32_16x16x32_bf16(ah, bh[m][q], acc[m], 0,0,0);
            }
            // E: nonlinearity (nx swizzled), h(t) -> LDS slot (t+1)&1
            u16* hbN = hbuf + ((t+1)&1)*4224;
#pragma unroll
            for (int u=0; u<2; ++u) {
                const int j = 32*w + 16*u + n16;
                const floatx4 nx4 = *(const floatx4*)(g0 + NX_OFF(j, quad));
#pragma unroll
                for (int r=0; r<4; ++r) {
                    const int b = quad*4 + r;
                    float rr = sigmoidf_(acc[u][r]);
                    float zz = sigmoidf_(acc[2+u][r]);
                    float nn = tanhf_(nx4[r] + rr*acc[4+u][r]);
                    float hp = bf2f(hbP[b*264 + j]);
                    float hn = nn + zz*(hp - nn);
                    hbN[b*264 + j] = f2bf(hn);
                }
            }
            // F: staging waves keep TWO steps' DMAs in flight (r11-exact).
            if (t < 6 || t >= SEQ-7) {
                wait_vm0();
            } else if (wu == 0) {
                WVC(17);
            } else if (wu < 4) {
                WVC(16);
            }                               // wu>=4: acks float
            lgkm_barrier();
        }
        // epilogue: h(511)/out(511) live in slot (512&1)=0
        const u16* hbL = hbuf;
        if (wu >= 4) {
            if (s<=4) {
                const int idx = tid - 256;
                const int b = idx & 15, k = (idx >> 4) & 15;
                char* hq = (char*)(hhb + (size_t)s*1048576 + (size_t)(SEQ-1)*2048);
                st16_sc1(hq + b*256 + k*16, *(const floatx4*)(hbL + b*264 + 8*k));
            } else {
                const int off = (s==6)?256:0;
#pragma unroll
                for (int k=0;k<3;++k) {
                    const int idx = (tid-256) + 256*k;
                    if (idx < 640) {
                        const int b = idx >> 6, jg = (idx & 63)*4;
                        union { u64 q; u16 h[4]; } v; v.q = *(const u64*)(hbL + b*264 + jg);
                        float4 o; o.x=bf2f(v.h[0]); o.y=bf2f(v.h[1]); o.z=bf2f(v.h[2]); o.w=bf2f(v.h[3]);
                        *(float4*)(out + (size_t)(SEQ-1)*5120 + (size_t)b*512 + off + jg) = o;
                    }
                }
            }
        }
        wait_vm0(); lgkm_barrier();
        if (tid==0 && s<=4) {
            AST(htp + 506, 507u); AST(htp + 507, 508u);
            AST(htp + 508, 509u); AST(htp + 509, 510u);
            AST(htp + 510, 511u); AST(htp + 511, 512u);
        }
        return;
    }

    // ================= HELPERS: gates_x producers (6 WGs/stream) =================
    const int sh = (blk - 7) / 6;
    const int t0 = (blk - 7) % 6;

    const int layer = (sh==6)?5:sh, dir=(sh==6)?1:0;
    const float* wihp; int stride;
    if (layer==0){ wihp = wihl0 + (size_t)dir*768*128; stride=128; }
    else         { wihp = wihrest + ((size_t)((layer-1)*2+dir))*768*512; stride=512; }

    short8 bxf[6][4];
#pragma unroll
    for (int i=0; i<6; ++i) {
        const int col = (w*6+i)*16 + n16;
#pragma unroll
        for (int q=0; q<4; ++q)
            bxf[i][q] = ld8f(wihp + (size_t)col*stride + q*32 + quad*8);
    }
    char* tb = (char*)smem_;               // 32 KB slot image
    const int bmA = (n16>9)?9:n16;
    const int lsrc = (sh==6)? 4 : (sh-1);
    u32* gtp_sh = tags + sh*32;

    // Software-pipelined publish: stores at iter t; wait_vm0 + tag at the
    // NEXT iteration (t+6) => store-ack has ~one full T_h of slack.
    int tprev = -1;
    for (int t = t0; t < SEQ; t += 6) {
        if (t >= 32) {   // ring-32 flow control vs consumer scan (lead <= ~24)
            int gd=0;
            while ((int)ALD(cparr + sh) < t-24){ if(++gd>1000000) break; __builtin_amdgcn_s_sleep(8); }
        }
        if (tprev >= 0) {
            wait_vm0();            // own wave's slot-(tprev) stores acked
            __syncthreads();       // all waves acked (+ all tb readers done)
            if (tid==0) AST(gtp_sh + (tprev&31), (u32)(tprev+1));
        }
        short8 ax[4];
        if (sh == 0) {
            const float* xr = x + (size_t)t*1280 + (size_t)bmA*128;
#pragma unroll
            for (int q=0; q<4; ++q) ax[q] = ld8f(xr + q*32 + quad*8);
        } else {
            const int srct = (sh==6)? (SEQ-1-t) : t;
            int gd=0;
            while (ALD(tags + 256 + lsrc*512 + srct) != (u32)(srct+1)){ if(++gd>3000000) break; __builtin_amdgcn_s_sleep(4); }
            const u64* hq = (const u64*)(hhb + (size_t)lsrc*1048576 + (size_t)srct*2048);
#pragma unroll
            for (int q=0; q<4; ++q) {
                u64 a = ALD(hq + n16*32 + q*8 + quad*2);
                u64 b = ALD(hq + n16*32 + q*8 + quad*2 + 1);
                ax[q] = pk2(a, b);
            }
        }
        floatx4 acc[6];
#pragma unroll
        for (int i=0; i<6; ++i) acc[i] = (floatx4){0.f,0.f,0.f,0.f};
#pragma unroll
        for (int q=0; q<4; ++q)
#pragma unroll
            for (int i=0; i<6; ++i)
                acc[i] = __builtin_amdgcn_mfma_f32_16x16x32_bf16(ax[q], bxf[i][q], acc[i], 0,0,0);

        // slot image (SWIZZLED): rz bf16 + nx f32; matches scan-side reads
        // (tb overwrite safe: tag barrier above drained all readers)
#pragma unroll
        for (int i=0; i<6; ++i) {
            const int col = (w*6+i)*16 + n16;
            if (col < 512) *(u64*)(tb + RZ_OFF(col, quad)) = pack4bf(acc[i]);
            else           *(floatx4*)(tb + NX_OFF(col-512, quad)) = acc[i];
        }
        __syncthreads();
        char* gq = (char*)(gring + (size_t)(sh*32 + (t&31))*GSLOT_U64);
#pragma unroll
        for (int k=0;k<4;++k)
            st16_sc1(gq + tid*64 + k*16, *(const floatx4*)((const char*)tb + tid*64 + k*16));
        tprev = t;
    }
    wait_vm0(); __syncthreads();
    if (tid==0 && tprev>=0) AST(gtp_sh + (tprev&31), (u32)(tprev+1));
}

extern "C" void kernel_launch(void* const* d_in, const int* in_sizes, int n_in,
                              void* d_out, int out_size, void* d_ws, size_t ws_size,
                              hipStream_t stream) {
    (void)in_sizes; (void)n_in; (void)out_size; (void)ws_size;
    const float* x       = (const float*)d_in[0];
    const float* wihl0   = (const float*)d_in[1];
    const float* wihrest = (const float*)d_in[2];
    const float* whh     = (const float*)d_in[3];
    float* out = (float*)d_out;
    u64* gring = (u64*)d_ws;
    u16* hhb   = (u16*)((char*)d_ws + (size_t)GRING_U64*8);
    u32* tags  = (u32*)((char*)d_ws + TAGS_OFF_B);

    // No memset: 0xAAAAAAAA poison never equals a valid tag (1..512);
    // flow-control reads cast to int; stale/poison LDS tag mirrors => bounded
    // slow poll (no deadlock; all barriers unconditional).
    gru_pipeline<<<dim3(49), dim3(512), 0, stream>>>(x, wihl0, wihrest, whh, out,
                                                     gring, hhb, tags);
}